// Round 1
// baseline (91.740 us; speedup 1.0000x reference)
//
#include <hip/hip_runtime.h>
#include <math.h>

#define NB 4
#define FRAMES 400
#define NBINS 129
#define HOP 240
#define T_LEN (FRAMES * HOP)   // 96000
#define KLEN 256               // FIR length = 2*(NBINS-1)

// ---------------------------------------------------------------------------
// Kernel 1: per (b,frame) compute the windowed minimum-phase FIR (256 taps).
// full[] is an even real sequence -> its DFT is real; all steps become real
// cos/sin-table DFT sums.
// ---------------------------------------------------------------------------
__global__ __launch_bounds__(256) void gen_fir(const float* __restrict__ log_mag,
                                               float* __restrict__ kern) {
    const int bf = blockIdx.x;   // 0..NB*FRAMES-1
    const int n  = threadIdx.x;  // 0..255

    __shared__ float full[KLEN];
    __shared__ float ctab[KLEN];
    __shared__ float stab[KLEN];
    __shared__ float g[KLEN];    // Xf[k]/128
    __shared__ float cr[KLEN];   // e^full * cos(mp)
    __shared__ float ci[KLEN];   // e^full * sin(mp)

    const float* lm = log_mag + bf * NBINS;
    // symmetric extension: full[n] = lm[n] (n<=128), lm[256-n] (n>=129)
    full[n] = (n < NBINS) ? lm[n] : lm[KLEN - n];

    float s, c;
    sincosf((float)n * 0.02454369260617026f /* 2*pi/256 */, &s, &c);
    ctab[n] = c;
    stab[n] = s;
    __syncthreads();

    // Xf[n] = sum_m full[m] cos(2*pi*n*m/256)   (real because full is even)
    float acc = 0.0f;
#pragma unroll 8
    for (int m = 0; m < KLEN; ++m)
        acc = fmaf(full[m], ctab[(n * m) & 255], acc);
    g[n] = acc * (1.0f / 128.0f);
    __syncthreads();

    // mp[n] = -(1/128) sum_{k=1..127} Xf[k] sin(2*pi*k*n/256)
    float mp = 0.0f;
#pragma unroll 8
    for (int k = 1; k < 128; ++k)
        mp = fmaf(g[k], stab[(k * n) & 255], mp);
    mp = -mp;

    float e = expf(full[n]);
    float smp, cmp_;
    sincosf(mp, &smp, &cmp_);
    cr[n] = e * cmp_;
    ci[n] = e * smp;
    __syncthreads();

    // ker[n] = (1/256) sum_k e^{full[k]} cos(mp[k] + 2*pi*k*n/256)
    acc = 0.0f;
#pragma unroll 8
    for (int k = 0; k < KLEN; ++k) {
        const int idx = (k * n) & 255;
        acc = fmaf(cr[k], ctab[idx], acc);
        acc = fmaf(-ci[k], stab[idx], acc);
    }
    float ker = acc * (1.0f / 256.0f);

    // windowing: first half 1.0, second half Hann tail
    const float wn = (n < KLEN / 2) ? 1.0f : (0.5f - 0.5f * ctab[n]);
    kern[bf * KLEN + n] = ker * wn;
}

// ---------------------------------------------------------------------------
// Kernel 2: time-varying FIR with linear kernel interpolation between frames.
// y[b,t] = (1-w)*sum_j x[t-j]*ker[lo][j] + w*sum_j x[t-j]*ker[hi][j]
// One block of 256 threads handles 256 consecutive outputs of one batch.
// ---------------------------------------------------------------------------
__global__ __launch_bounds__(256) void fir_apply(const float* __restrict__ ex,
                                                 const float* __restrict__ kern,
                                                 float* __restrict__ out) {
    const int b   = blockIdx.y;
    const int t0  = blockIdx.x * 256;
    const int tid = threadIdx.x;

    __shared__ float xs[512];        // x[t0-255 .. t0+255]
    __shared__ float kl[4 * 257];    // up to 4 frame kernels, padded stride 257

    for (int i = tid; i < 511; i += 256) {
        const int t = t0 - 255 + i;
        xs[i] = (t >= 0) ? ex[b * T_LEN + t] : 0.0f;
    }

    // frames needed by this block: f0 .. f0+3 (clamped)
    float src0 = (t0 + 0.5f) / (float)HOP - 0.5f;
    src0 = fminf(fmaxf(src0, 0.0f), (float)(FRAMES - 1));
    const int f0 = (int)floorf(src0);
    for (int i = tid; i < 4 * KLEN; i += 256) {
        const int gidx = i >> 8;
        const int j    = i & 255;
        const int fr   = min(f0 + gidx, FRAMES - 1);
        kl[gidx * 257 + j] = kern[(b * FRAMES + fr) * KLEN + j];
    }
    __syncthreads();

    const int t = t0 + tid;
    float src = (t + 0.5f) / (float)HOP - 0.5f;
    src = fminf(fmaxf(src, 0.0f), (float)(FRAMES - 1));
    const int lo = (int)floorf(src);
    const int hi = min(lo + 1, FRAMES - 1);
    const float w = src - (float)lo;

    const float* kerL = &kl[(lo - f0) * 257];
    const float* kerH = &kl[(hi - f0) * 257];

    float acc0 = 0.0f, acc1 = 0.0f;
#pragma unroll 8
    for (int j = 0; j < KLEN; ++j) {
        const float xv = xs[tid + 255 - j];
        acc0 = fmaf(xv, kerL[j], acc0);
        acc1 = fmaf(xv, kerH[j], acc1);
    }
    out[b * T_LEN + t] = (1.0f - w) * acc0 + w * acc1;
}

// ---------------------------------------------------------------------------
extern "C" void kernel_launch(void* const* d_in, const int* in_sizes, int n_in,
                              void* d_out, int out_size, void* d_ws, size_t ws_size,
                              hipStream_t stream) {
    const float* ex      = (const float*)d_in[0];
    const float* log_mag = (const float*)d_in[1];
    float* kern = (float*)d_ws;          // NB*FRAMES*KLEN floats = 1.6 MB
    float* out  = (float*)d_out;

    gen_fir<<<NB * FRAMES, 256, 0, stream>>>(log_mag, kern);

    dim3 grid(T_LEN / 256, NB);
    fir_apply<<<grid, 256, 0, stream>>>(ex, kern, out);
}

// Round 2
// 44.879 us; speedup vs baseline: 2.0441x; 2.0441x over previous
//
#include <hip/hip_runtime.h>
#include <math.h>

#define NB 4
#define FRAMES 400
#define NBINS 129
#define HOP 240
#define T_LEN (FRAMES * HOP)   // 96000
#define KLEN 256               // FIR length = 2*(NBINS-1)

// ---------------------------------------------------------------------------
// Kernel 1: per (b,frame) windowed minimum-phase FIR (256 taps).
// All DFT sums via per-thread Chebyshev recurrences (no LDS tables ->
// no bank conflicts; only wave-uniform broadcast reads).
// Symmetry used: full[] even -> Xf real & even; mp odd; cr even, ci odd.
// All three sums fold to k = 1..127.
// ---------------------------------------------------------------------------
__global__ __launch_bounds__(256) void gen_fir(const float* __restrict__ log_mag,
                                               float* __restrict__ kern) {
    const int bf = blockIdx.x;   // 0..NB*FRAMES-1
    const int n  = threadIdx.x;  // 0..255

    __shared__ float full[NBINS];     // only 0..128 needed (even extension)
    __shared__ float g[128];          // Xf[k]/128, k=1..127 used
    __shared__ float cr2[129];        // 2*e^full*cos(mp), k=0..128
    __shared__ float ci2[129];        // 2*e^full*sin(mp), k=0..128

    const float* lm = log_mag + bf * NBINS;
    if (n < NBINS) full[n] = lm[n];

    // angle alpha = 2*pi*n/256; recurrence coefficient 2*cos(alpha)
    float sa, ca;
    sincosf((float)n * 0.02454369260617026f, &sa, &ca);
    const float a2 = 2.0f * ca;
    const float sgn = (n & 1) ? -1.0f : 1.0f;   // (-1)^n
    __syncthreads();

    // ---- Xf[n] = full[0] + (-1)^n full[128] + 2*sum_{m=1..127} full[m] cos(m n a)
    {
        float cm1 = 1.0f, cm = ca, acc = 0.0f;
#pragma unroll 8
        for (int m = 1; m < 128; ++m) {
            acc = fmaf(full[m], cm, acc);
            const float cn = fmaf(a2, cm, -cm1);
            cm1 = cm; cm = cn;
        }
        const float Xf = full[0] + sgn * full[128] + 2.0f * acc;
        if (n < 128) g[n] = Xf * (1.0f / 128.0f);
    }
    __syncthreads();

    // ---- mp[n] = -sum_{k=1..127} g[k] sin(k n a); only k<=128 of cr/ci consumed
    if (n <= 128) {
        float sm1 = 0.0f, sm = sa, acc = 0.0f;
#pragma unroll 8
        for (int k = 1; k < 128; ++k) {
            acc = fmaf(g[k], sm, acc);
            const float sn = fmaf(a2, sm, -sm1);
            sm1 = sm; sm = sn;
        }
        const float mp = -acc;
        const float e = expf(full[n]);
        float smp, cmp_;
        sincosf(mp, &smp, &cmp_);
        cr2[n] = 2.0f * e * cmp_;
        ci2[n] = 2.0f * e * smp;
    }
    __syncthreads();

    // ---- ker[n] = (1/256)[ cr[0] + (-1)^n cr[128]
    //                        + sum_{k=1..127} (cr2[k] cos(k n a) - ci2[k] sin(k n a)) ]
    {
        float cm1 = 1.0f, cm = ca;
        float sm1 = 0.0f, sm = sa;
        float acc = 0.0f;
#pragma unroll 8
        for (int k = 1; k < 128; ++k) {
            acc = fmaf(cr2[k], cm, acc);
            acc = fmaf(-ci2[k], sm, acc);
            const float cn = fmaf(a2, cm, -cm1);
            cm1 = cm; cm = cn;
            const float sn = fmaf(a2, sm, -sm1);
            sm1 = sm; sm = sn;
        }
        const float ker = (0.5f * cr2[0] + sgn * 0.5f * cr2[128] + acc) * (1.0f / 256.0f);

        // windowing: first half 1.0, second half Hann tail 0.5-0.5*cos(2*pi*n/256)
        const float wn = (n < KLEN / 2) ? 1.0f : (0.5f - 0.5f * ca);
        kern[bf * KLEN + n] = ker * wn;
    }
}

// ---------------------------------------------------------------------------
// Kernel 2: time-varying FIR with linear kernel interpolation between frames.
// y[b,t] = (1-w)*sum_j x[t-j]*ker[lo][j] + w*sum_j x[t-j]*ker[hi][j]
// One block of 256 threads handles 256 consecutive outputs of one batch.
// ---------------------------------------------------------------------------
__global__ __launch_bounds__(256) void fir_apply(const float* __restrict__ ex,
                                                 const float* __restrict__ kern,
                                                 float* __restrict__ out) {
    const int b   = blockIdx.y;
    const int t0  = blockIdx.x * 256;
    const int tid = threadIdx.x;

    __shared__ float xs[512];        // x[t0-255 .. t0+255]
    __shared__ float kl[4 * 257];    // up to 4 frame kernels, padded stride 257

    for (int i = tid; i < 511; i += 256) {
        const int t = t0 - 255 + i;
        xs[i] = (t >= 0) ? ex[b * T_LEN + t] : 0.0f;
    }

    // frames needed by this block: f0 .. f0+3 (clamped)
    float src0 = (t0 + 0.5f) / (float)HOP - 0.5f;
    src0 = fminf(fmaxf(src0, 0.0f), (float)(FRAMES - 1));
    const int f0 = (int)floorf(src0);
    for (int i = tid; i < 4 * KLEN; i += 256) {
        const int gidx = i >> 8;
        const int j    = i & 255;
        const int fr   = min(f0 + gidx, FRAMES - 1);
        kl[gidx * 257 + j] = kern[(b * FRAMES + fr) * KLEN + j];
    }
    __syncthreads();

    const int t = t0 + tid;
    float src = (t + 0.5f) / (float)HOP - 0.5f;
    src = fminf(fmaxf(src, 0.0f), (float)(FRAMES - 1));
    const int lo = (int)floorf(src);
    const int hi = min(lo + 1, FRAMES - 1);
    const float w = src - (float)lo;

    const float* kerL = &kl[(lo - f0) * 257];
    const float* kerH = &kl[(hi - f0) * 257];

    float acc0 = 0.0f, acc1 = 0.0f;
#pragma unroll 8
    for (int j = 0; j < KLEN; ++j) {
        const float xv = xs[tid + 255 - j];
        acc0 = fmaf(xv, kerL[j], acc0);
        acc1 = fmaf(xv, kerH[j], acc1);
    }
    out[b * T_LEN + t] = (1.0f - w) * acc0 + w * acc1;
}

// ---------------------------------------------------------------------------
extern "C" void kernel_launch(void* const* d_in, const int* in_sizes, int n_in,
                              void* d_out, int out_size, void* d_ws, size_t ws_size,
                              hipStream_t stream) {
    const float* ex      = (const float*)d_in[0];
    const float* log_mag = (const float*)d_in[1];
    float* kern = (float*)d_ws;          // NB*FRAMES*KLEN floats = 1.6 MB
    float* out  = (float*)d_out;

    gen_fir<<<NB * FRAMES, 256, 0, stream>>>(log_mag, kern);

    dim3 grid(T_LEN / 256, NB);
    fir_apply<<<grid, 256, 0, stream>>>(ex, kern, out);
}

// Round 3
// 24.670 us; speedup vs baseline: 3.7187x; 1.8192x over previous
//
#include <hip/hip_runtime.h>
#include <math.h>

#define NB 4
#define FRAMES 400
#define NBINS 129
#define HOP 240
#define T_LEN (FRAMES * HOP)   // 96000
#define KLEN 256               // FIR length = 2*(NBINS-1)

// ---------------------------------------------------------------------------
// Kernel 1: per (b,frame) windowed minimum-phase FIR (256 taps), 128 threads.
// Thread n computes ker[n] AND ker[n+128] via parity split:
//   cos(k(n+128)*2pi/256) = (-1)^k cos(kn*2pi/256)
// All coefficient reads are float4 LDS broadcasts; trig via Chebyshev
// recurrences (c_{k+1} = 2cos(a) c_k - c_{k-1}).
// mp[0] = mp[128] = 0 analytically -> edge terms are just e^full.
// ---------------------------------------------------------------------------
__global__ __launch_bounds__(128) void gen_fir(const float* __restrict__ log_mag,
                                               float* __restrict__ kern) {
    const int bf = blockIdx.x;   // 0..NB*FRAMES-1
    const int n  = threadIdx.x;  // 0..127

    __shared__ __align__(16) float  full[132];   // lm[0..128]
    __shared__ __align__(16) float  g[128];      // Xf[k]/128, k=0..127 (g[0] unused->0 coeff)
    __shared__ __align__(16) float2 crci[128];   // (cr2[k], ci2[k]) k=0..127; k=0 pre-halved

    const float* lm = log_mag + bf * NBINS;
    full[n] = lm[n];
    if (n == 0) full[128] = lm[128];

    float sa, ca;
    sincosf((float)n * 0.02454369260617026f /* 2*pi/256 */, &sa, &ca);
    const float a2  = 2.0f * ca;
    const float sgn = (n & 1) ? -1.0f : 1.0f;   // (-1)^n
    __syncthreads();

    const float full0 = full[0];
    const float full128 = full[128];

    // ---- Xf[n] = 2*sum_{m=0..127} full[m] cos(mna) - full[0] + sgn*full[128]
    {
        const float4* f4p = (const float4*)full;
        float cm1 = ca, cm = 1.0f, acc = 0.0f;   // c_{-1}=cos(-a), c_0=1
#pragma unroll 8
        for (int u = 0; u < 32; ++u) {
            const float4 f4 = f4p[u];
            acc = fmaf(f4.x, cm, acc); { const float cn = fmaf(a2, cm, -cm1); cm1 = cm; cm = cn; }
            acc = fmaf(f4.y, cm, acc); { const float cn = fmaf(a2, cm, -cm1); cm1 = cm; cm = cn; }
            acc = fmaf(f4.z, cm, acc); { const float cn = fmaf(a2, cm, -cm1); cm1 = cm; cm = cn; }
            acc = fmaf(f4.w, cm, acc); { const float cn = fmaf(a2, cm, -cm1); cm1 = cm; cm = cn; }
        }
        const float Xf = 2.0f * acc - full0 + sgn * full128;
        g[n] = Xf * (1.0f / 128.0f);
    }
    __syncthreads();

    // ---- mp[n] = -sum_{k=0..127} g[k] sin(kna)   (k=0 term is 0)
    {
        const float4* g4p = (const float4*)g;
        float sm1 = -sa, sm = 0.0f, acc = 0.0f;  // s_{-1}=sin(-a), s_0=0
#pragma unroll 8
        for (int u = 0; u < 32; ++u) {
            const float4 gv = g4p[u];
            acc = fmaf(gv.x, sm, acc); { const float sn = fmaf(a2, sm, -sm1); sm1 = sm; sm = sn; }
            acc = fmaf(gv.y, sm, acc); { const float sn = fmaf(a2, sm, -sm1); sm1 = sm; sm = sn; }
            acc = fmaf(gv.z, sm, acc); { const float sn = fmaf(a2, sm, -sm1); sm1 = sm; sm = sn; }
            acc = fmaf(gv.w, sm, acc); { const float sn = fmaf(a2, sm, -sm1); sm1 = sm; sm = sn; }
        }
        const float mp = -acc;
        const float e  = expf(full[n]);
        float smp, cmp_;
        sincosf(mp, &smp, &cmp_);
        const float sc = (n == 0) ? 1.0f : 2.0f;   // k=0 edge carries weight 1/2
        crci[n] = make_float2(sc * e * cmp_, sc * e * smp);
    }
    __syncthreads();

    // ---- ker[n]     = (accE + accO + sgn*e128)/256
    //      ker[n+128] = (accE - accO + sgn*e128)/256 * hann(n+128)
    {
        const float e128 = expf(full128);
        const float4* cc4 = (const float4*)crci;
        float cm1 = ca, cm = 1.0f;     // k=0
        float sm1 = -sa, sm = 0.0f;
        float accE = 0.0f, accO = 0.0f;
#pragma unroll 8
        for (int u = 0; u < 64; ++u) {
            const float4 q = cc4[u];   // cr2[2u], ci2[2u], cr2[2u+1], ci2[2u+1]
            accE = fmaf(q.x, cm, accE); accE = fmaf(-q.y, sm, accE);
            { const float cn = fmaf(a2, cm, -cm1); cm1 = cm; cm = cn;
              const float sn = fmaf(a2, sm, -sm1); sm1 = sm; sm = sn; }
            accO = fmaf(q.z, cm, accO); accO = fmaf(-q.w, sm, accO);
            { const float cn = fmaf(a2, cm, -cm1); cm1 = cm; cm = cn;
              const float sn = fmaf(a2, sm, -sm1); sm1 = sm; sm = sn; }
        }
        const float base = sgn * e128;
        const float k0 = (accE + accO + base) * (1.0f / 256.0f);                         // wn=1
        const float k1 = (accE - accO + base) * (1.0f / 256.0f) * (0.5f + 0.5f * ca);    // hann tail
        kern[bf * KLEN + n]       = k0;
        kern[bf * KLEN + n + 128] = k1;
    }
}

// ---------------------------------------------------------------------------
// Kernel 2: time-varying FIR. 256 threads, each computes 2 ADJACENT outputs
// (te=t0+2i, te+1). Frame boundaries sit between odd->even t, so a pair always
// shares (lo,hi) -> no divergence. Kernel pair interleaved as float2 so one
// ds_read_b128 fetches 2 taps of both kernels; x via one b64 + register carry.
// Per 2 taps: 2 LDS insts, 8 FMAs.
// ---------------------------------------------------------------------------
__global__ __launch_bounds__(256) void fir_apply(const float* __restrict__ ex,
                                                 const float* __restrict__ kern,
                                                 float* __restrict__ out) {
    const int b   = blockIdx.y;
    const int t0  = blockIdx.x * 512;
    const int tid = threadIdx.x;

    __shared__ __align__(16) float  xs[768];        // x[t0-255 .. t0+511]
    __shared__ __align__(16) float2 kp[4][258];     // (kerLo[j], kerHi[j]) per q; +2 pad de-aliases banks

    for (int i = tid; i < 768; i += 256) {
        const int t = t0 - 255 + i;
        xs[i] = (t >= 0 && t < T_LEN) ? ex[b * T_LEN + t] : 0.0f;
    }

    float src0 = ((float)t0 + 0.5f) * (1.0f / HOP) - 0.5f;
    src0 = fminf(fmaxf(src0, 0.0f), (float)(FRAMES - 1));
    const int f0 = (int)src0;
    const float* kb = kern + b * FRAMES * KLEN;
    for (int i = tid; i < 4 * 256; i += 256) {
        const int q = i >> 8, j = i & 255;
        const int fl = min(f0 + q,     FRAMES - 1);
        const int fh = min(f0 + q + 1, FRAMES - 1);
        kp[q][j] = make_float2(kb[fl * KLEN + j], kb[fh * KLEN + j]);
    }
    __syncthreads();

    const int te = t0 + 2 * tid;
    float se = ((float)te + 0.5f) * (1.0f / HOP) - 0.5f;
    se = fminf(fmaxf(se, 0.0f), (float)(FRAMES - 1));
    float so = ((float)te + 1.5f) * (1.0f / HOP) - 0.5f;
    so = fminf(fmaxf(so, 0.0f), (float)(FRAMES - 1));
    const int   lo = (int)se;           // == lo(te+1), boundary-safe by parity
    const float we = se - (float)lo;
    const float wo = so - (float)lo;

    const float4* kq4 = (const float4*)&kp[lo - f0][0];   // (kL[2u],kH[2u],kL[2u+1],kH[2u+1])

    const int base = 2 * tid;           // xs index of x[te] is base+255
    float carry = xs[base + 256];       // x[te+1]
    float aeL = 0.0f, aeH = 0.0f, aoL = 0.0f, aoH = 0.0f;
#pragma unroll 8
    for (int u = 0; u < 128; ++u) {
        const float2 v  = *(const float2*)&xs[base + 254 - 2 * u];  // (x[te-2u-1], x[te-2u])
        const float4 k4 = kq4[u];
        aeL = fmaf(v.y,   k4.x, aeL);  aeH = fmaf(v.y,   k4.y, aeH);   // out e, j=2u
        aoL = fmaf(carry, k4.x, aoL);  aoH = fmaf(carry, k4.y, aoH);   // out o, j=2u
        aeL = fmaf(v.x,   k4.z, aeL);  aeH = fmaf(v.x,   k4.w, aeH);   // out e, j=2u+1
        aoL = fmaf(v.y,   k4.z, aoL);  aoH = fmaf(v.y,   k4.w, aoH);   // out o, j=2u+1
        carry = v.x;
    }

    if (te < T_LEN)     out[b * T_LEN + te]     = (1.0f - we) * aeL + we * aeH;
    if (te + 1 < T_LEN) out[b * T_LEN + te + 1] = (1.0f - wo) * aoL + wo * aoH;
}

// ---------------------------------------------------------------------------
extern "C" void kernel_launch(void* const* d_in, const int* in_sizes, int n_in,
                              void* d_out, int out_size, void* d_ws, size_t ws_size,
                              hipStream_t stream) {
    const float* ex      = (const float*)d_in[0];
    const float* log_mag = (const float*)d_in[1];
    float* kern = (float*)d_ws;          // NB*FRAMES*KLEN floats = 1.6 MB
    float* out  = (float*)d_out;

    gen_fir<<<NB * FRAMES, 128, 0, stream>>>(log_mag, kern);

    dim3 grid((T_LEN + 511) / 512, NB);
    fir_apply<<<grid, 256, 0, stream>>>(ex, kern, out);
}